// Round 16
// baseline (441.100 us; speedup 1.0000x reference)
//
#include <hip/hip_runtime.h>

#define METAc 3
#define Nn 50000
#define NP1 50001   // rows per graph incl. dummy zero row at index Nn
#define Ee 640000
#define CHUNK 1024
#define NCH 49   // ceil(Nn/CHUNK)
#define NXCD 8
#define FILL_WPX 256   // workgroups per XCD-slice for k_fill2

typedef unsigned int uint;
typedef unsigned short ushort;
typedef unsigned char uchar;
typedef __attribute__((ext_vector_type(8))) short bf16x8;
typedef __attribute__((ext_vector_type(4))) float f32x4;
typedef __attribute__((ext_vector_type(2))) float f32x2;
typedef __attribute__((ext_vector_type(4))) uint uint4v;   // native vector: OK for nontemporal builtins

// decode 2 packed OCP-fp8(e4m3) from low/high word of a uint -> float2 (1 VALU op)
#define CVT8LO(w) ((f32x2)__builtin_amdgcn_cvt_pk_f32_fp8((w), false))
#define CVT8HI(w) ((f32x2)__builtin_amdgcn_cvt_pk_f32_fp8((w), true))

__device__ __forceinline__ float bf2f(uint u16) {
    union { uint u; float f; } v; v.u = u16 << 16; return v.f;
}
__device__ __forceinline__ uint f2bf(float f) {
    union { float f; uint u; } v; v.f = f;
    return (v.u + 0x7fffu + ((v.u >> 16) & 1u)) >> 16;
}
__device__ __forceinline__ uchar f2fp8(float f) {
    return (uchar)(__builtin_amdgcn_cvt_pk_fp8_f32(f, f, 0u, false) & 0xffu);
}
// unpack 2 packed bf16 -> float2 {lo, hi}; add is 1 v_pk_add_f32
__device__ __forceinline__ f32x2 up2(uint u) {
    union { uint2 u2; f32x2 f; } cv;
    cv.u2.x = u << 16;
    cv.u2.y = u & 0xffff0000u;
    return cv.f;
}
__device__ __forceinline__ f32x4 mfma16(bf16x8 a, bf16x8 b, f32x4 c) {
    return __builtin_amdgcn_mfma_f32_16x16x32_bf16(a, b, c, 0, 0, 0);
}
__device__ __forceinline__ uint4v nt_load4(const void* p) {
    return __builtin_nontemporal_load((const uint4v*)p);
}

// ================= CSR build =================
__global__ __launch_bounds__(256) void k_count(const int* __restrict__ ei, int* __restrict__ cnt,
                                               uint* __restrict__ packed) {
    int idx = blockIdx.x * 256 + threadIdx.x;
    if (idx >= METAc * (Ee / 4)) return;
    int m = idx / (Ee / 4), e4 = idx - m * (Ee / 4);
    const int* base = ei + (size_t)m * 2 * Ee;
    uint4v d = nt_load4(base + Ee + e4 * 4);
    uint4v s = nt_load4(base + e4 * 4);
    int* cm = cnt + m * Nn;
    atomicAdd(cm + (int)d.x, 1);
    atomicAdd(cm + (int)d.y, 1);
    atomicAdd(cm + (int)d.z, 1);
    atomicAdd(cm + (int)d.w, 1);
    uint4v p;
    p.x = (s.x & 0xffffu) | (d.x << 16);
    p.y = (s.y & 0xffffu) | (d.y << 16);
    p.z = (s.z & 0xffffu) | (d.z << 16);
    p.w = (s.w & 0xffffu) | (d.w << 16);
    *(uint4v*)(packed + (size_t)m * Ee + e4 * 4) = p;
}

__global__ __launch_bounds__(1024) void k_chunksum(const int* __restrict__ cnt, int* __restrict__ csum) {
    int m = blockIdx.x / NCH, ch = blockIdx.x - m * NCH;
    int tid = threadIdx.x;
    int i = ch * CHUNK + tid;
    int v = (i < Nn) ? cnt[m * Nn + i] : 0;
    #pragma unroll
    for (int o = 1; o < 64; o <<= 1) v += __shfl_xor(v, o);
    __shared__ int ws_[16];
    int lane = tid & 63, w = tid >> 6;
    if (lane == 0) ws_[w] = v;
    __syncthreads();
    if (tid == 0) {
        int s = 0;
        #pragma unroll
        for (int k = 0; k < 16; k++) s += ws_[k];
        csum[m * 64 + ch] = s;
    }
}

__global__ __launch_bounds__(256) void k_chunkscan(int* __restrict__ csum) {
    int tid = threadIdx.x;
    int w = tid >> 6, lane = tid & 63;
    if (w >= METAc) return;
    int v = (lane < NCH) ? csum[w * 64 + lane] : 0;
    int orig = v;
    #pragma unroll
    for (int o = 1; o < 64; o <<= 1) { int t = __shfl_up(v, o); if (lane >= o) v += t; }
    if (lane < NCH) csum[w * 64 + lane] = v - orig;
}

__global__ __launch_bounds__(1024) void k_scan(const int* __restrict__ cnt, const int* __restrict__ csum,
                                               int* __restrict__ off, int* __restrict__ cur,
                                               float* __restrict__ inv) {
    int m = blockIdx.x / NCH, ch = blockIdx.x - m * NCH;
    int tid = threadIdx.x;
    int i = ch * CHUNK + tid;
    int c = (i < Nn) ? cnt[m * Nn + i] : 0;
    int lane = tid & 63, w = tid >> 6;
    int v = c;
    #pragma unroll
    for (int o = 1; o < 64; o <<= 1) { int t = __shfl_up(v, o); if (lane >= o) v += t; }
    __shared__ int ws_[16];
    if (lane == 63) ws_[w] = v;
    __syncthreads();
    if (tid < 16) {
        int s = ws_[tid];
        #pragma unroll
        for (int o = 1; o < 16; o <<= 1) { int t = __shfl_up(s, o); if (lane >= o) s += t; }
        ws_[tid] = s;
    }
    __syncthreads();
    int base = (w > 0) ? ws_[w - 1] : 0;
    if (i < Nn) {
        int g = csum[m * 64 + ch] + base + v - c;
        off[m * Nn + i] = g;
        cur[m * Nn + i] = g;
        inv[m * Nn + i] = 1.0f / fmaxf((float)c, 1.0f);
    }
}

// XCD-local CSR fill from the PACKED edge stream.
__global__ __launch_bounds__(256) void k_fill2(const uint* __restrict__ packed, int* __restrict__ cur,
                                               ushort* __restrict__ esrc) {
    const int xcd = blockIdx.x & (NXCD - 1);
    const int wslice = blockIdx.x >> 3;
    const int total4 = METAc * (Ee / 4);
    const int chunk4 = (total4 + FILL_WPX - 1) / FILL_WPX;
    const int beg = wslice * chunk4;
    const int end = (beg + chunk4 < total4) ? beg + chunk4 : total4;
    const int lo = xcd * (Nn / NXCD);
    const int hi = lo + (Nn / NXCD);
    for (int idx = beg + threadIdx.x; idx < end; idx += 256) {
        int m = idx / (Ee / 4), e4 = idx - m * (Ee / 4);
        uint4v p = nt_load4(packed + (size_t)m * Ee + e4 * 4);
        int* cm = cur + m * Nn;
        ushort* em = esrc + (size_t)m * Ee;
        int dd;
        dd = (int)(p.x >> 16); if (dd >= lo && dd < hi) { int q = atomicAdd(cm + dd, 1); em[q] = (ushort)(p.x & 0xffffu); }
        dd = (int)(p.y >> 16); if (dd >= lo && dd < hi) { int q = atomicAdd(cm + dd, 1); em[q] = (ushort)(p.y & 0xffffu); }
        dd = (int)(p.z >> 16); if (dd >= lo && dd < hi) { int q = atomicAdd(cm + dd, 1); em[q] = (ushort)(p.z & 0xffffu); }
        dd = (int)(p.w >> 16); if (dd >= lo && dd < hi) { int q = atomicAdd(cm + dd, 1); em[q] = (ushort)(p.w & 0xffffu); }
    }
}

// ============ weight prep ============
__global__ __launch_bounds__(256) void k_wcat(
    const float* __restrict__ W1l, const float* __restrict__ W1r,
    const float* __restrict__ W2l, const float* __restrict__ W2r,
    ushort* __restrict__ Wcat1, ushort* __restrict__ Wcat2)
{
    int idx = blockIdx.x * 256 + threadIdx.x;
    if (idx >= METAc * 384 * 128) return;
    int m = idx / (384 * 128);
    int rem = idx - m * 384 * 128;
    int j = rem >> 7;
    int k = rem & 127;
    if (j < 256) {
        float v = (j < 128) ? W1l[((size_t)m * 128 + k) * 128 + j]
                            : W1r[((size_t)m * 128 + k) * 128 + (j - 128)];
        Wcat1[((size_t)m * 256 + j) * 128 + k] = (ushort)f2bf(v);
    } else {
        int j2 = j - 256;
        float v = (j2 < 64) ? W2l[((size_t)m * 128 + k) * 64 + j2]
                            : W2r[((size_t)m * 128 + k) * 64 + (j2 - 64)];
        Wcat2[((size_t)m * 128 + j2) * 128 + k] = (ushort)f2bf(v);
    }
}

// zero the per-graph dummy rows of t1 (fp8) and t2 (bf16)
__global__ __launch_bounds__(128) void k_zerodummy(uchar* __restrict__ t1, ushort* __restrict__ t2) {
    int m = blockIdx.x;
    int tid = threadIdx.x;
    t1[((size_t)m * NP1 + Nn) * 128 + tid] = 0;
    if (tid < 64) t2[((size_t)m * NP1 + Nn) * 64 + tid] = 0;
}

// ============ MFMA GEMM1: t1 (fp8, stride NP1) and r1 (bf16, +b1) = x @ {W1l, W1r} ============
__global__ __launch_bounds__(256) void k_mfma1(
    const float* __restrict__ x, const ushort* __restrict__ Wcat1,
    const float* __restrict__ b1, uchar* __restrict__ t1, ushort* __restrict__ r1)
{
    const int m = blockIdx.y;
    const int row0 = blockIdx.x * 128;
    const int tid = threadIdx.x;
    const int lane = tid & 63, w = tid >> 6;
    const int wr = w >> 1, wc = w & 1;

    __shared__ ushort As[128][136];   // 272B rows: 2-way bank aliasing only
    __shared__ ushort Bs[128][136];

    const float* Am = x + (size_t)m * Nn * 128;

    #pragma unroll
    for (int i = 0; i < 16; i++) {
        int f4 = tid + i * 256;
        int row = f4 >> 5, c4 = f4 & 31;
        int gr = row0 + row; if (gr >= Nn) gr = Nn - 1;
        float4 v = *(const float4*)(Am + (size_t)gr * 128 + c4 * 4);
        uint lo = f2bf(v.x) | (f2bf(v.y) << 16);
        uint hi = f2bf(v.z) | (f2bf(v.w) << 16);
        *(uint2*)&As[row][c4 * 4] = make_uint2(lo, hi);
    }

    for (int z = 0; z < 2; z++) {
        const ushort* Bm = Wcat1 + ((size_t)m * 256 + (size_t)z * 128) * 128;
        if (z) __syncthreads();
        #pragma unroll
        for (int i = 0; i < 8; i++) {
            int c8 = tid + i * 256;
            int row = c8 >> 4, c = c8 & 15;
            *(bf16x8*)&Bs[row][c * 8] = *(const bf16x8*)(Bm + (size_t)row * 128 + c * 8);
        }
        __syncthreads();

        f32x4 acc[4][4];
        #pragma unroll
        for (int i = 0; i < 4; i++)
            #pragma unroll
            for (int j = 0; j < 4; j++) acc[i][j] = (f32x4){0.f, 0.f, 0.f, 0.f};

        #pragma unroll
        for (int ks = 0; ks < 4; ks++) {
            bf16x8 a[4], b[4];
            #pragma unroll
            for (int i = 0; i < 4; i++)
                a[i] = *(const bf16x8*)&As[wr * 64 + i * 16 + (lane & 15)][ks * 32 + (lane >> 4) * 8];
            #pragma unroll
            for (int j = 0; j < 4; j++)
                b[j] = *(const bf16x8*)&Bs[wc * 64 + j * 16 + (lane & 15)][ks * 32 + (lane >> 4) * 8];
            #pragma unroll
            for (int i = 0; i < 4; i++)
                #pragma unroll
                for (int j = 0; j < 4; j++)
                    acc[i][j] = mfma16(a[i], b[j], acc[i][j]);
        }

        if (z == 0) {
            uchar* outp = t1 + (size_t)m * NP1 * 128;
            #pragma unroll
            for (int j = 0; j < 4; j++) {
                int col = wc * 64 + j * 16 + (lane & 15);
                #pragma unroll
                for (int i = 0; i < 4; i++) {
                    #pragma unroll
                    for (int q = 0; q < 4; q++) {
                        int row = row0 + wr * 64 + i * 16 + (lane >> 4) * 4 + q;
                        if (row < Nn)
                            outp[(size_t)row * 128 + col] = f2fp8(acc[i][j][q]);
                    }
                }
            }
        } else {
            ushort* outp = r1 + (size_t)m * Nn * 128;
            #pragma unroll
            for (int j = 0; j < 4; j++) {
                int col = wc * 64 + j * 16 + (lane & 15);
                float bias = b1[m * 128 + col];
                #pragma unroll
                for (int i = 0; i < 4; i++) {
                    #pragma unroll
                    for (int q = 0; q < 4; q++) {
                        int row = row0 + wr * 64 + i * 16 + (lane >> 4) * 4 + q;
                        if (row < Nn)
                            outp[(size_t)row * 128 + col] = (ushort)f2bf(acc[i][j][q] + bias);
                    }
                }
            }
        }
    }
}

// ============ MFMA GEMM2: t2 (bf16, stride NP1) / r2 (bf16, +b2) = h @ Wcat2 ============
__global__ __launch_bounds__(256) void k_mfma2(
    const ushort* __restrict__ h, const ushort* __restrict__ Wcat2,
    const float* __restrict__ b2, ushort* __restrict__ t2, ushort* __restrict__ r2)
{
    const int m = blockIdx.y;
    const int row0 = blockIdx.x * 128;
    const int tid = threadIdx.x;
    const int lane = tid & 63, w = tid >> 6;
    const int wr = w >> 1, wc = w & 1;

    __shared__ ushort As[128][136];
    __shared__ ushort Bs[128][136];

    const ushort* Am = h + (size_t)m * Nn * 128;
    const ushort* Bm = Wcat2 + (size_t)m * 128 * 128;

    #pragma unroll
    for (int i = 0; i < 8; i++) {
        int c8 = tid + i * 256;
        int row = c8 >> 4, c = c8 & 15;
        int gr = row0 + row; if (gr >= Nn) gr = Nn - 1;
        *(bf16x8*)&As[row][c * 8] = *(const bf16x8*)(Am + (size_t)gr * 128 + c * 8);
    }
    #pragma unroll
    for (int i = 0; i < 8; i++) {
        int c8 = tid + i * 256;
        int row = c8 >> 4, c = c8 & 15;
        *(bf16x8*)&Bs[row][c * 8] = *(const bf16x8*)(Bm + (size_t)row * 128 + c * 8);
    }
    __syncthreads();

    f32x4 acc[4][4];
    #pragma unroll
    for (int i = 0; i < 4; i++)
        #pragma unroll
        for (int j = 0; j < 4; j++) acc[i][j] = (f32x4){0.f, 0.f, 0.f, 0.f};

    #pragma unroll
    for (int ks = 0; ks < 4; ks++) {
        bf16x8 a[4], b[4];
        #pragma unroll
        for (int i = 0; i < 4; i++)
            a[i] = *(const bf16x8*)&As[wr * 64 + i * 16 + (lane & 15)][ks * 32 + (lane >> 4) * 8];
        #pragma unroll
        for (int j = 0; j < 4; j++)
            b[j] = *(const bf16x8*)&Bs[wc * 64 + j * 16 + (lane & 15)][ks * 32 + (lane >> 4) * 8];
        #pragma unroll
        for (int i = 0; i < 4; i++)
            #pragma unroll
            for (int j = 0; j < 4; j++)
                acc[i][j] = mfma16(a[i], b[j], acc[i][j]);
    }

    ushort* outp = wc ? (r2 + (size_t)m * Nn * 64) : (t2 + (size_t)m * NP1 * 64);
    #pragma unroll
    for (int j = 0; j < 4; j++) {
        int cl = j * 16 + (lane & 15);
        float bias = wc ? b2[m * 64 + cl] : 0.0f;
        #pragma unroll
        for (int i = 0; i < 4; i++) {
            #pragma unroll
            for (int q = 0; q < 4; q++) {
                int row = row0 + wr * 64 + i * 16 + (lane >> 4) * 4 + q;
                if (row < Nn)
                    outp[(size_t)row * 64 + cl] = (ushort)f2bf(acc[i][j][q] + bias);
            }
        }
    }
}

// ============ agg1: h = ELU(mean-gather(t1 fp8) + r1), bf16 out ============
// Branch-free 32-edge prologue: 4 gathers/lane in flight, OOB slots -> dummy
// zero row Nn (stride NP1). Wave-uniform tail for c>32 (≈never at deg~12.8).
__global__ __launch_bounds__(256) void k_agg_elu(
    const uchar* __restrict__ t1, const ushort* __restrict__ r1,
    const int* __restrict__ off, const int* __restrict__ cnt,
    const float* __restrict__ inv, const ushort* __restrict__ esrc,
    ushort* __restrict__ h)
{
    int gwid = (blockIdx.x * 256 + threadIdx.x) >> 6;
    if (gwid >= METAc * Nn) return;
    int m = gwid / Nn, n = gwid - m * Nn;
    int lane = threadIdx.x & 63;
    int g = lane >> 3;        // 0..7: edge slot
    int sub = lane & 7;       // 8 lanes x 16B = 128B fp8 row
    int start = off[m * Nn + n];
    int c = cnt[m * Nn + n];
    const ushort* es = esrc + (size_t)m * Ee + start;
    const uchar* tm = t1 + (size_t)m * NP1 * 128;

    // unconditional idx loads (mapped-safe), select dummy row for e>=c
    int v0 = es[g], v1 = es[g + 8], v2 = es[g + 16], v3 = es[g + 24];
    int i0 = (g      < c) ? v0 : Nn;
    int i1 = (g + 8  < c) ? v1 : Nn;
    int i2 = (g + 16 < c) ? v2 : Nn;
    int i3 = (g + 24 < c) ? v3 : Nn;
    uint4 w0 = *(const uint4*)(tm + (size_t)i0 * 128 + sub * 16);
    uint4 w1 = *(const uint4*)(tm + (size_t)i1 * 128 + sub * 16);
    uint4 w2 = *(const uint4*)(tm + (size_t)i2 * 128 + sub * 16);
    uint4 w3 = *(const uint4*)(tm + (size_t)i3 * 128 + sub * 16);

    f32x2 a[8];
    #pragma unroll
    for (int k = 0; k < 8; k++) a[k] = (f32x2){0.f, 0.f};
    a[0] += CVT8LO(w0.x); a[1] += CVT8HI(w0.x);
    a[2] += CVT8LO(w0.y); a[3] += CVT8HI(w0.y);
    a[4] += CVT8LO(w0.z); a[5] += CVT8HI(w0.z);
    a[6] += CVT8LO(w0.w); a[7] += CVT8HI(w0.w);
    a[0] += CVT8LO(w1.x); a[1] += CVT8HI(w1.x);
    a[2] += CVT8LO(w1.y); a[3] += CVT8HI(w1.y);
    a[4] += CVT8LO(w1.z); a[5] += CVT8HI(w1.z);
    a[6] += CVT8LO(w1.w); a[7] += CVT8HI(w1.w);
    a[0] += CVT8LO(w2.x); a[1] += CVT8HI(w2.x);
    a[2] += CVT8LO(w2.y); a[3] += CVT8HI(w2.y);
    a[4] += CVT8LO(w2.z); a[5] += CVT8HI(w2.z);
    a[6] += CVT8LO(w2.w); a[7] += CVT8HI(w2.w);
    a[0] += CVT8LO(w3.x); a[1] += CVT8HI(w3.x);
    a[2] += CVT8LO(w3.y); a[3] += CVT8HI(w3.y);
    a[4] += CVT8LO(w3.z); a[5] += CVT8HI(w3.z);
    a[6] += CVT8LO(w3.w); a[7] += CVT8HI(w3.w);

    if (c > 32) {   // wave-uniform branch; essentially never taken
        for (int e = 32 + g; e < c; e += 8) {
            int s0 = es[e];
            uint4 v = *(const uint4*)(tm + (size_t)s0 * 128 + sub * 16);
            a[0] += CVT8LO(v.x); a[1] += CVT8HI(v.x);
            a[2] += CVT8LO(v.y); a[3] += CVT8HI(v.y);
            a[4] += CVT8LO(v.z); a[5] += CVT8HI(v.z);
            a[6] += CVT8LO(v.w); a[7] += CVT8HI(v.w);
        }
    }

    // reduce the 8 edge-slots (lane bits 3,4,5)
    #pragma unroll
    for (int k = 0; k < 8; k++) {
        a[k].x += __shfl_xor(a[k].x, 8);   a[k].y += __shfl_xor(a[k].y, 8);
        a[k].x += __shfl_xor(a[k].x, 16);  a[k].y += __shfl_xor(a[k].y, 16);
        a[k].x += __shfl_xor(a[k].x, 32);  a[k].y += __shfl_xor(a[k].y, 32);
    }

    float iv = inv[m * Nn + n];
    const uint* rrow = (const uint*)(r1 + ((size_t)m * Nn + n) * 128);
    uint4 rv0 = *(const uint4*)(rrow + sub * 8);
    uint4 rv1 = *(const uint4*)(rrow + sub * 8 + 4);
    uint rw[8] = {rv0.x, rv0.y, rv0.z, rv0.w, rv1.x, rv1.y, rv1.z, rv1.w};
    uint o[8];
    #pragma unroll
    for (int k = 0; k < 8; k++) {
        float z0 = a[k].x * iv + bf2f(rw[k] & 0xffffu);
        float z1 = a[k].y * iv + bf2f(rw[k] >> 16);
        z0 = z0 > 0.0f ? z0 : (__expf(z0) - 1.0f);
        z1 = z1 > 0.0f ? z1 : (__expf(z1) - 1.0f);
        o[k] = f2bf(z0) | (f2bf(z1) << 16);
    }
    if (g == 0) {
        uint* hrow = (uint*)(h + ((size_t)m * Nn + n) * 128) + sub * 8;
        *(uint4*)hrow       = make_uint4(o[0], o[1], o[2], o[3]);
        *(uint4*)(hrow + 4) = make_uint4(o[4], o[5], o[6], o[7]);
    }
}

// ============ agg2: out = log_softmax(mean-gather(t2 bf16) + r2) ============
// Same branch-free 32-edge prologue (dummy row Nn, stride NP1).
__global__ __launch_bounds__(256) void k_agg_lsm(
    const ushort* __restrict__ t2, const ushort* __restrict__ r2,
    const int* __restrict__ off, const int* __restrict__ cnt,
    const float* __restrict__ inv, const ushort* __restrict__ esrc,
    float* __restrict__ out)
{
    int gwid = (blockIdx.x * 256 + threadIdx.x) >> 6;
    if (gwid >= METAc * Nn) return;
    int m = gwid / Nn, n = gwid - m * Nn;
    int lane = threadIdx.x & 63;
    int g = lane >> 3;        // 0..7: edge slot
    int sub = lane & 7;       // 8 lanes x 16B = 128B row
    int start = off[m * Nn + n];
    int c = cnt[m * Nn + n];
    const ushort* es = esrc + (size_t)m * Ee + start;
    const ushort* tm = t2 + (size_t)m * NP1 * 64;

    int v0 = es[g], v1 = es[g + 8], v2 = es[g + 16], v3 = es[g + 24];
    int i0 = (g      < c) ? v0 : Nn;
    int i1 = (g + 8  < c) ? v1 : Nn;
    int i2 = (g + 16 < c) ? v2 : Nn;
    int i3 = (g + 24 < c) ? v3 : Nn;
    uint4 w0 = *(const uint4*)(tm + (size_t)i0 * 64 + sub * 8);
    uint4 w1 = *(const uint4*)(tm + (size_t)i1 * 64 + sub * 8);
    uint4 w2 = *(const uint4*)(tm + (size_t)i2 * 64 + sub * 8);
    uint4 w3 = *(const uint4*)(tm + (size_t)i3 * 64 + sub * 8);

    f32x2 a[4];
    #pragma unroll
    for (int k = 0; k < 4; k++) a[k] = (f32x2){0.f, 0.f};
    a[0] += up2(w0.x); a[1] += up2(w0.y); a[2] += up2(w0.z); a[3] += up2(w0.w);
    a[0] += up2(w1.x); a[1] += up2(w1.y); a[2] += up2(w1.z); a[3] += up2(w1.w);
    a[0] += up2(w2.x); a[1] += up2(w2.y); a[2] += up2(w2.z); a[3] += up2(w2.w);
    a[0] += up2(w3.x); a[1] += up2(w3.y); a[2] += up2(w3.z); a[3] += up2(w3.w);

    if (c > 32) {
        for (int e = 32 + g; e < c; e += 8) {
            int s0 = es[e];
            uint4 v = *(const uint4*)(tm + (size_t)s0 * 64 + sub * 8);
            a[0] += up2(v.x); a[1] += up2(v.y); a[2] += up2(v.z); a[3] += up2(v.w);
        }
    }

    #pragma unroll
    for (int k = 0; k < 4; k++) {
        a[k].x += __shfl_xor(a[k].x, 8);   a[k].y += __shfl_xor(a[k].y, 8);
        a[k].x += __shfl_xor(a[k].x, 16);  a[k].y += __shfl_xor(a[k].y, 16);
        a[k].x += __shfl_xor(a[k].x, 32);  a[k].y += __shfl_xor(a[k].y, 32);
    }

    float iv = inv[m * Nn + n];
    uint4 rv = *(const uint4*)(r2 + ((size_t)m * Nn + n) * 64 + sub * 8);
    uint rr[4] = {rv.x, rv.y, rv.z, rv.w};
    float z[8];
    #pragma unroll
    for (int k = 0; k < 4; k++) {
        z[2 * k]     = a[k].x * iv + bf2f(rr[k] & 0xffffu);
        z[2 * k + 1] = a[k].y * iv + bf2f(rr[k] >> 16);
    }
    float mx = z[0];
    #pragma unroll
    for (int k = 1; k < 8; k++) mx = fmaxf(mx, z[k]);
    #pragma unroll
    for (int o = 1; o <= 4; o <<= 1) mx = fmaxf(mx, __shfl_xor(mx, o));
    float s = 0.0f;
    #pragma unroll
    for (int k = 0; k < 8; k++) s += __expf(z[k] - mx);
    #pragma unroll
    for (int o = 1; o <= 4; o <<= 1) s += __shfl_xor(s, o);
    float lse = mx + __logf(s);
    if (g == 0) {
        float* op = out + ((size_t)m * Nn + n) * 64 + sub * 8;
        *(float4*)op       = make_float4(z[0] - lse, z[1] - lse, z[2] - lse, z[3] - lse);
        *(float4*)(op + 4) = make_float4(z[4] - lse, z[5] - lse, z[6] - lse, z[7] - lse);
    }
}

extern "C" void kernel_launch(void* const* d_in, const int* in_sizes, int n_in,
                              void* d_out, int out_size, void* d_ws, size_t ws_size,
                              hipStream_t stream) {
    const float* meta_x = (const float*)d_in[0];
    const int*   ei     = (const int*)d_in[1];
    const float* W1l    = (const float*)d_in[2];
    const float* W1r    = (const float*)d_in[3];
    const float* b1     = (const float*)d_in[4];
    const float* W2l    = (const float*)d_in[5];
    const float* W2r    = (const float*)d_in[6];
    const float* b2     = (const float*)d_in[7];
    float* out = (float*)d_out;

    const size_t nN = (size_t)METAc * Nn;
    const size_t nP = (size_t)METAc * NP1;

    float* inv  = (float*)d_ws;
    int*   cnt  = (int*)(inv + nN);
    int*   off  = cnt + nN;
    int*   cur  = off + nN;
    int*   csum = cur + nN;
    uint*  packed = (uint*)(csum + 64 * METAc);         // META*E packed (src|dst<<16)
    ushort* esrc = (ushort*)(packed + (size_t)METAc * Ee);
    uchar* t1   = (uchar*)(esrc + (size_t)METAc * Ee);  // fp8 e4m3, [m][NP1][128]
    ushort* r1  = (ushort*)(t1 + nP * 128);
    ushort* h   = r1 + nN * 128;
    ushort* t2  = h + nN * 128;                         // bf16, [m][NP1][64]
    ushort* r2  = t2 + nP * 64;
    ushort* Wcat1 = r2 + nN * 64;                       // META*256*128
    ushort* Wcat2 = Wcat1 + (size_t)METAc * 256 * 128;  // META*128*128

    (void)hipMemsetAsync(cnt, 0, nN * sizeof(int), stream);
    k_count<<<(METAc * (Ee / 4) + 255) / 256, 256, 0, stream>>>(ei, cnt, packed);
    k_chunksum<<<METAc * NCH, 1024, 0, stream>>>(cnt, csum);
    k_chunkscan<<<1, 256, 0, stream>>>(csum);
    k_scan<<<METAc * NCH, 1024, 0, stream>>>(cnt, csum, off, cur, inv);
    k_fill2<<<NXCD * FILL_WPX, 256, 0, stream>>>(packed, cur, esrc);
    k_wcat<<<(METAc * 384 * 128 + 255) / 256, 256, 0, stream>>>(W1l, W1r, W2l, W2r, Wcat1, Wcat2);
    k_zerodummy<<<METAc, 128, 0, stream>>>(t1, t2);

    k_mfma1<<<dim3((Nn + 127) / 128, METAc), 256, 0, stream>>>(meta_x, Wcat1, b1, t1, r1);
    k_agg_elu<<<(METAc * Nn * 64 + 255) / 256, 256, 0, stream>>>(t1, r1, off, cnt, inv, esrc, h);
    k_mfma2<<<dim3((Nn + 127) / 128, METAc), 256, 0, stream>>>(h, Wcat2, b2, t2, r2);
    k_agg_lsm<<<(METAc * Nn * 64 + 255) / 256, 256, 0, stream>>>(t2, r2, off, cnt, inv, esrc, out);
}

// Round 17
// 363.649 us; speedup vs baseline: 1.2130x; 1.2130x over previous
//
#include <hip/hip_runtime.h>

#define METAc 3
#define Nn 50000
#define Ee 640000
#define CHUNK 1024
#define NCH 49   // ceil(Nn/CHUNK)
#define NXCD 8
#define FILL_WPX 256   // workgroups per XCD-slice for k_fill2

typedef unsigned int uint;
typedef unsigned short ushort;
typedef unsigned char uchar;
typedef __attribute__((ext_vector_type(8))) short bf16x8;
typedef __attribute__((ext_vector_type(4))) float f32x4;
typedef __attribute__((ext_vector_type(2))) float f32x2;
typedef __attribute__((ext_vector_type(4))) uint uint4v;   // native vector: OK for nontemporal builtins

// decode 2 packed OCP-fp8(e4m3) from low/high word of a uint -> float2 (1 VALU op)
#define CVT8LO(w) ((f32x2)__builtin_amdgcn_cvt_pk_f32_fp8((w), false))
#define CVT8HI(w) ((f32x2)__builtin_amdgcn_cvt_pk_f32_fp8((w), true))

__device__ __forceinline__ float bf2f(uint u16) {
    union { uint u; float f; } v; v.u = u16 << 16; return v.f;
}
__device__ __forceinline__ uint f2bf(float f) {
    union { float f; uint u; } v; v.f = f;
    return (v.u + 0x7fffu + ((v.u >> 16) & 1u)) >> 16;
}
__device__ __forceinline__ uchar f2fp8(float f) {
    return (uchar)(__builtin_amdgcn_cvt_pk_fp8_f32(f, f, 0u, false) & 0xffu);
}
// unpack 2 packed bf16 -> float2 {lo, hi}; add is 1 v_pk_add_f32
__device__ __forceinline__ f32x2 up2(uint u) {
    union { uint2 u2; f32x2 f; } cv;
    cv.u2.x = u << 16;
    cv.u2.y = u & 0xffff0000u;
    return cv.f;
}
__device__ __forceinline__ f32x4 mfma16(bf16x8 a, bf16x8 b, f32x4 c) {
    return __builtin_amdgcn_mfma_f32_16x16x32_bf16(a, b, c, 0, 0, 0);
}
__device__ __forceinline__ uint4v nt_load4(const void* p) {
    return __builtin_nontemporal_load((const uint4v*)p);
}

// ================= CSR build =================
__global__ __launch_bounds__(256) void k_count(const int* __restrict__ ei, int* __restrict__ cnt,
                                               uint* __restrict__ packed) {
    int idx = blockIdx.x * 256 + threadIdx.x;
    if (idx >= METAc * (Ee / 4)) return;
    int m = idx / (Ee / 4), e4 = idx - m * (Ee / 4);
    const int* base = ei + (size_t)m * 2 * Ee;
    uint4v d = nt_load4(base + Ee + e4 * 4);
    uint4v s = nt_load4(base + e4 * 4);
    int* cm = cnt + m * Nn;
    atomicAdd(cm + (int)d.x, 1);
    atomicAdd(cm + (int)d.y, 1);
    atomicAdd(cm + (int)d.z, 1);
    atomicAdd(cm + (int)d.w, 1);
    uint4v p;
    p.x = (s.x & 0xffffu) | (d.x << 16);
    p.y = (s.y & 0xffffu) | (d.y << 16);
    p.z = (s.z & 0xffffu) | (d.z << 16);
    p.w = (s.w & 0xffffu) | (d.w << 16);
    *(uint4v*)(packed + (size_t)m * Ee + e4 * 4) = p;
}

__global__ __launch_bounds__(1024) void k_chunksum(const int* __restrict__ cnt, int* __restrict__ csum) {
    int m = blockIdx.x / NCH, ch = blockIdx.x - m * NCH;
    int tid = threadIdx.x;
    int i = ch * CHUNK + tid;
    int v = (i < Nn) ? cnt[m * Nn + i] : 0;
    #pragma unroll
    for (int o = 1; o < 64; o <<= 1) v += __shfl_xor(v, o);
    __shared__ int ws_[16];
    int lane = tid & 63, w = tid >> 6;
    if (lane == 0) ws_[w] = v;
    __syncthreads();
    if (tid == 0) {
        int s = 0;
        #pragma unroll
        for (int k = 0; k < 16; k++) s += ws_[k];
        csum[m * 64 + ch] = s;
    }
}

__global__ __launch_bounds__(256) void k_chunkscan(int* __restrict__ csum) {
    int tid = threadIdx.x;
    int w = tid >> 6, lane = tid & 63;
    if (w >= METAc) return;
    int v = (lane < NCH) ? csum[w * 64 + lane] : 0;
    int orig = v;
    #pragma unroll
    for (int o = 1; o < 64; o <<= 1) { int t = __shfl_up(v, o); if (lane >= o) v += t; }
    if (lane < NCH) csum[w * 64 + lane] = v - orig;
}

__global__ __launch_bounds__(1024) void k_scan(const int* __restrict__ cnt, const int* __restrict__ csum,
                                               int* __restrict__ off, int* __restrict__ cur,
                                               float* __restrict__ inv) {
    int m = blockIdx.x / NCH, ch = blockIdx.x - m * NCH;
    int tid = threadIdx.x;
    int i = ch * CHUNK + tid;
    int c = (i < Nn) ? cnt[m * Nn + i] : 0;
    int lane = tid & 63, w = tid >> 6;
    int v = c;
    #pragma unroll
    for (int o = 1; o < 64; o <<= 1) { int t = __shfl_up(v, o); if (lane >= o) v += t; }
    __shared__ int ws_[16];
    if (lane == 63) ws_[w] = v;
    __syncthreads();
    if (tid < 16) {
        int s = ws_[tid];
        #pragma unroll
        for (int o = 1; o < 16; o <<= 1) { int t = __shfl_up(s, o); if (lane >= o) s += t; }
        ws_[tid] = s;
    }
    __syncthreads();
    int base = (w > 0) ? ws_[w - 1] : 0;
    if (i < Nn) {
        int g = csum[m * 64 + ch] + base + v - c;
        off[m * Nn + i] = g;
        cur[m * Nn + i] = g;
        inv[m * Nn + i] = 1.0f / fmaxf((float)c, 1.0f);
    }
}

// XCD-local CSR fill from the PACKED edge stream.
__global__ __launch_bounds__(256) void k_fill2(const uint* __restrict__ packed, int* __restrict__ cur,
                                               ushort* __restrict__ esrc) {
    const int xcd = blockIdx.x & (NXCD - 1);
    const int wslice = blockIdx.x >> 3;
    const int total4 = METAc * (Ee / 4);
    const int chunk4 = (total4 + FILL_WPX - 1) / FILL_WPX;
    const int beg = wslice * chunk4;
    const int end = (beg + chunk4 < total4) ? beg + chunk4 : total4;
    const int lo = xcd * (Nn / NXCD);
    const int hi = lo + (Nn / NXCD);
    for (int idx = beg + threadIdx.x; idx < end; idx += 256) {
        int m = idx / (Ee / 4), e4 = idx - m * (Ee / 4);
        uint4v p = nt_load4(packed + (size_t)m * Ee + e4 * 4);
        int* cm = cur + m * Nn;
        ushort* em = esrc + (size_t)m * Ee;
        int dd;
        dd = (int)(p.x >> 16); if (dd >= lo && dd < hi) { int q = atomicAdd(cm + dd, 1); em[q] = (ushort)(p.x & 0xffffu); }
        dd = (int)(p.y >> 16); if (dd >= lo && dd < hi) { int q = atomicAdd(cm + dd, 1); em[q] = (ushort)(p.y & 0xffffu); }
        dd = (int)(p.z >> 16); if (dd >= lo && dd < hi) { int q = atomicAdd(cm + dd, 1); em[q] = (ushort)(p.z & 0xffffu); }
        dd = (int)(p.w >> 16); if (dd >= lo && dd < hi) { int q = atomicAdd(cm + dd, 1); em[q] = (ushort)(p.w & 0xffffu); }
    }
}

// ============ weight prep ============
__global__ __launch_bounds__(256) void k_wcat(
    const float* __restrict__ W1l, const float* __restrict__ W1r,
    const float* __restrict__ W2l, const float* __restrict__ W2r,
    ushort* __restrict__ Wcat1, ushort* __restrict__ Wcat2)
{
    int idx = blockIdx.x * 256 + threadIdx.x;
    if (idx >= METAc * 384 * 128) return;
    int m = idx / (384 * 128);
    int rem = idx - m * 384 * 128;
    int j = rem >> 7;
    int k = rem & 127;
    if (j < 256) {
        float v = (j < 128) ? W1l[((size_t)m * 128 + k) * 128 + j]
                            : W1r[((size_t)m * 128 + k) * 128 + (j - 128)];
        Wcat1[((size_t)m * 256 + j) * 128 + k] = (ushort)f2bf(v);
    } else {
        int j2 = j - 256;
        float v = (j2 < 64) ? W2l[((size_t)m * 128 + k) * 64 + j2]
                            : W2r[((size_t)m * 128 + k) * 64 + (j2 - 64)];
        Wcat2[((size_t)m * 128 + j2) * 128 + k] = (ushort)f2bf(v);
    }
}

// ============ MFMA GEMM1: t1 (fp8) and r1 (bf16, +b1) = x @ {W1l, W1r} ============
__global__ __launch_bounds__(256) void k_mfma1(
    const float* __restrict__ x, const ushort* __restrict__ Wcat1,
    const float* __restrict__ b1, uchar* __restrict__ t1, ushort* __restrict__ r1)
{
    const int m = blockIdx.y;
    const int row0 = blockIdx.x * 128;
    const int tid = threadIdx.x;
    const int lane = tid & 63, w = tid >> 6;
    const int wr = w >> 1, wc = w & 1;

    __shared__ ushort As[128][136];   // 272B rows: 2-way bank aliasing only
    __shared__ ushort Bs[128][136];

    const float* Am = x + (size_t)m * Nn * 128;

    #pragma unroll
    for (int i = 0; i < 16; i++) {
        int f4 = tid + i * 256;
        int row = f4 >> 5, c4 = f4 & 31;
        int gr = row0 + row; if (gr >= Nn) gr = Nn - 1;
        float4 v = *(const float4*)(Am + (size_t)gr * 128 + c4 * 4);
        uint lo = f2bf(v.x) | (f2bf(v.y) << 16);
        uint hi = f2bf(v.z) | (f2bf(v.w) << 16);
        *(uint2*)&As[row][c4 * 4] = make_uint2(lo, hi);
    }

    for (int z = 0; z < 2; z++) {
        const ushort* Bm = Wcat1 + ((size_t)m * 256 + (size_t)z * 128) * 128;
        if (z) __syncthreads();
        #pragma unroll
        for (int i = 0; i < 8; i++) {
            int c8 = tid + i * 256;
            int row = c8 >> 4, c = c8 & 15;
            *(bf16x8*)&Bs[row][c * 8] = *(const bf16x8*)(Bm + (size_t)row * 128 + c * 8);
        }
        __syncthreads();

        f32x4 acc[4][4];
        #pragma unroll
        for (int i = 0; i < 4; i++)
            #pragma unroll
            for (int j = 0; j < 4; j++) acc[i][j] = (f32x4){0.f, 0.f, 0.f, 0.f};

        #pragma unroll
        for (int ks = 0; ks < 4; ks++) {
            bf16x8 a[4], b[4];
            #pragma unroll
            for (int i = 0; i < 4; i++)
                a[i] = *(const bf16x8*)&As[wr * 64 + i * 16 + (lane & 15)][ks * 32 + (lane >> 4) * 8];
            #pragma unroll
            for (int j = 0; j < 4; j++)
                b[j] = *(const bf16x8*)&Bs[wc * 64 + j * 16 + (lane & 15)][ks * 32 + (lane >> 4) * 8];
            #pragma unroll
            for (int i = 0; i < 4; i++)
                #pragma unroll
                for (int j = 0; j < 4; j++)
                    acc[i][j] = mfma16(a[i], b[j], acc[i][j]);
        }

        if (z == 0) {
            uchar* outp = t1 + (size_t)m * Nn * 128;
            #pragma unroll
            for (int j = 0; j < 4; j++) {
                int col = wc * 64 + j * 16 + (lane & 15);
                #pragma unroll
                for (int i = 0; i < 4; i++) {
                    #pragma unroll
                    for (int q = 0; q < 4; q++) {
                        int row = row0 + wr * 64 + i * 16 + (lane >> 4) * 4 + q;
                        if (row < Nn)
                            outp[(size_t)row * 128 + col] = f2fp8(acc[i][j][q]);
                    }
                }
            }
        } else {
            ushort* outp = r1 + (size_t)m * Nn * 128;
            #pragma unroll
            for (int j = 0; j < 4; j++) {
                int col = wc * 64 + j * 16 + (lane & 15);
                float bias = b1[m * 128 + col];
                #pragma unroll
                for (int i = 0; i < 4; i++) {
                    #pragma unroll
                    for (int q = 0; q < 4; q++) {
                        int row = row0 + wr * 64 + i * 16 + (lane >> 4) * 4 + q;
                        if (row < Nn)
                            outp[(size_t)row * 128 + col] = (ushort)f2bf(acc[i][j][q] + bias);
                    }
                }
            }
        }
    }
}

// ============ MFMA GEMM2: t2 (bf16) / r2 (bf16, +b2) = h @ Wcat2 ============
__global__ __launch_bounds__(256) void k_mfma2(
    const ushort* __restrict__ h, const ushort* __restrict__ Wcat2,
    const float* __restrict__ b2, ushort* __restrict__ t2, ushort* __restrict__ r2)
{
    const int m = blockIdx.y;
    const int row0 = blockIdx.x * 128;
    const int tid = threadIdx.x;
    const int lane = tid & 63, w = tid >> 6;
    const int wr = w >> 1, wc = w & 1;

    __shared__ ushort As[128][136];
    __shared__ ushort Bs[128][136];

    const ushort* Am = h + (size_t)m * Nn * 128;
    const ushort* Bm = Wcat2 + (size_t)m * 128 * 128;

    #pragma unroll
    for (int i = 0; i < 8; i++) {
        int c8 = tid + i * 256;
        int row = c8 >> 4, c = c8 & 15;
        int gr = row0 + row; if (gr >= Nn) gr = Nn - 1;
        *(bf16x8*)&As[row][c * 8] = *(const bf16x8*)(Am + (size_t)gr * 128 + c * 8);
    }
    #pragma unroll
    for (int i = 0; i < 8; i++) {
        int c8 = tid + i * 256;
        int row = c8 >> 4, c = c8 & 15;
        *(bf16x8*)&Bs[row][c * 8] = *(const bf16x8*)(Bm + (size_t)row * 128 + c * 8);
    }
    __syncthreads();

    f32x4 acc[4][4];
    #pragma unroll
    for (int i = 0; i < 4; i++)
        #pragma unroll
        for (int j = 0; j < 4; j++) acc[i][j] = (f32x4){0.f, 0.f, 0.f, 0.f};

    #pragma unroll
    for (int ks = 0; ks < 4; ks++) {
        bf16x8 a[4], b[4];
        #pragma unroll
        for (int i = 0; i < 4; i++)
            a[i] = *(const bf16x8*)&As[wr * 64 + i * 16 + (lane & 15)][ks * 32 + (lane >> 4) * 8];
        #pragma unroll
        for (int j = 0; j < 4; j++)
            b[j] = *(const bf16x8*)&Bs[wc * 64 + j * 16 + (lane & 15)][ks * 32 + (lane >> 4) * 8];
        #pragma unroll
        for (int i = 0; i < 4; i++)
            #pragma unroll
            for (int j = 0; j < 4; j++)
                acc[i][j] = mfma16(a[i], b[j], acc[i][j]);
    }

    ushort* outp = (wc ? r2 : t2) + (size_t)m * Nn * 64;
    #pragma unroll
    for (int j = 0; j < 4; j++) {
        int cl = j * 16 + (lane & 15);
        float bias = wc ? b2[m * 64 + cl] : 0.0f;
        #pragma unroll
        for (int i = 0; i < 4; i++) {
            #pragma unroll
            for (int q = 0; q < 4; q++) {
                int row = row0 + wr * 64 + i * 16 + (lane >> 4) * 4 + q;
                if (row < Nn)
                    outp[(size_t)row * 64 + cl] = (ushort)f2bf(acc[i][j][q] + bias);
            }
        }
    }
}

// ============ agg1: h = ELU(mean-gather(t1 fp8) + r1), bf16 out ============
// One 8-lane group per NODE (8 nodes/wave). Group loops serially over its c
// edges (2 loads in flight); lane owns 16 of 128 columns. No cross-slot
// reduce, exactly-sized epilogue, decode work proportional to c.
__global__ __launch_bounds__(256) void k_agg_elu(
    const uchar* __restrict__ t1, const ushort* __restrict__ r1,
    const int* __restrict__ off, const int* __restrict__ cnt,
    const float* __restrict__ inv, const ushort* __restrict__ esrc,
    ushort* __restrict__ h)
{
    int lane = threadIdx.x & 63;
    int grp = lane >> 3;      // node slot within wave
    int sub = lane & 7;       // 16B column chunk (16 fp8)
    int node = ((blockIdx.x * 256 + threadIdx.x) >> 6) * 8 + grp;
    if (node >= METAc * Nn) return;
    int m = node / Nn, n = node - m * Nn;
    int start = off[m * Nn + n];
    int c = cnt[m * Nn + n];
    const ushort* es = esrc + (size_t)m * Ee + start;
    const uchar* tm = t1 + (size_t)m * Nn * 128;

    f32x2 a[8];
    #pragma unroll
    for (int k = 0; k < 8; k++) a[k] = (f32x2){0.f, 0.f};

    int e = 0;
    for (; e + 1 < c; e += 2) {
        int s0 = es[e], s1 = es[e + 1];
        uint4 v0 = *(const uint4*)(tm + (size_t)s0 * 128 + sub * 16);
        uint4 v1 = *(const uint4*)(tm + (size_t)s1 * 128 + sub * 16);
        a[0] += CVT8LO(v0.x); a[1] += CVT8HI(v0.x);
        a[2] += CVT8LO(v0.y); a[3] += CVT8HI(v0.y);
        a[4] += CVT8LO(v0.z); a[5] += CVT8HI(v0.z);
        a[6] += CVT8LO(v0.w); a[7] += CVT8HI(v0.w);
        a[0] += CVT8LO(v1.x); a[1] += CVT8HI(v1.x);
        a[2] += CVT8LO(v1.y); a[3] += CVT8HI(v1.y);
        a[4] += CVT8LO(v1.z); a[5] += CVT8HI(v1.z);
        a[6] += CVT8LO(v1.w); a[7] += CVT8HI(v1.w);
    }
    if (e < c) {
        int s0 = es[e];
        uint4 v0 = *(const uint4*)(tm + (size_t)s0 * 128 + sub * 16);
        a[0] += CVT8LO(v0.x); a[1] += CVT8HI(v0.x);
        a[2] += CVT8LO(v0.y); a[3] += CVT8HI(v0.y);
        a[4] += CVT8LO(v0.z); a[5] += CVT8HI(v0.z);
        a[6] += CVT8LO(v0.w); a[7] += CVT8HI(v0.w);
    }

    float iv = inv[m * Nn + n];
    // lane owns cols sub*16..sub*16+15 of the 128-col row (32B of bf16)
    const uint* rrow = (const uint*)(r1 + ((size_t)m * Nn + n) * 128);
    uint4 rv0 = *(const uint4*)(rrow + sub * 8);
    uint4 rv1 = *(const uint4*)(rrow + sub * 8 + 4);
    uint rw[8] = {rv0.x, rv0.y, rv0.z, rv0.w, rv1.x, rv1.y, rv1.z, rv1.w};
    uint o[8];
    #pragma unroll
    for (int k = 0; k < 8; k++) {
        float z0 = a[k].x * iv + bf2f(rw[k] & 0xffffu);
        float z1 = a[k].y * iv + bf2f(rw[k] >> 16);
        z0 = z0 > 0.0f ? z0 : (__expf(z0) - 1.0f);
        z1 = z1 > 0.0f ? z1 : (__expf(z1) - 1.0f);
        o[k] = f2bf(z0) | (f2bf(z1) << 16);
    }
    uint* hrow = (uint*)(h + ((size_t)m * Nn + n) * 128) + sub * 8;
    *(uint4*)hrow       = make_uint4(o[0], o[1], o[2], o[3]);
    *(uint4*)(hrow + 4) = make_uint4(o[4], o[5], o[6], o[7]);
}

// ============ agg2: out = log_softmax(mean-gather(t2 bf16) + r2) ============
// One 8-lane group per node; lane owns 8 of 64 cols; softmax reduce = 3
// intra-group shuffles.
__global__ __launch_bounds__(256) void k_agg_lsm(
    const ushort* __restrict__ t2, const ushort* __restrict__ r2,
    const int* __restrict__ off, const int* __restrict__ cnt,
    const float* __restrict__ inv, const ushort* __restrict__ esrc,
    float* __restrict__ out)
{
    int lane = threadIdx.x & 63;
    int grp = lane >> 3;
    int sub = lane & 7;       // 16B chunk = 8 bf16 cols
    int node = ((blockIdx.x * 256 + threadIdx.x) >> 6) * 8 + grp;
    if (node >= METAc * Nn) return;
    int m = node / Nn, n = node - m * Nn;
    int start = off[m * Nn + n];
    int c = cnt[m * Nn + n];
    const ushort* es = esrc + (size_t)m * Ee + start;
    const ushort* tm = t2 + (size_t)m * Nn * 64;

    f32x2 a[4];
    #pragma unroll
    for (int k = 0; k < 4; k++) a[k] = (f32x2){0.f, 0.f};

    int e = 0;
    for (; e + 1 < c; e += 2) {
        int s0 = es[e], s1 = es[e + 1];
        uint4 v0 = *(const uint4*)(tm + (size_t)s0 * 64 + sub * 8);
        uint4 v1 = *(const uint4*)(tm + (size_t)s1 * 64 + sub * 8);
        a[0] += up2(v0.x); a[1] += up2(v0.y); a[2] += up2(v0.z); a[3] += up2(v0.w);
        a[0] += up2(v1.x); a[1] += up2(v1.y); a[2] += up2(v1.z); a[3] += up2(v1.w);
    }
    if (e < c) {
        int s0 = es[e];
        uint4 v0 = *(const uint4*)(tm + (size_t)s0 * 64 + sub * 8);
        a[0] += up2(v0.x); a[1] += up2(v0.y); a[2] += up2(v0.z); a[3] += up2(v0.w);
    }

    float iv = inv[m * Nn + n];
    uint4 rv = *(const uint4*)(r2 + ((size_t)m * Nn + n) * 64 + sub * 8);
    uint rr[4] = {rv.x, rv.y, rv.z, rv.w};
    float z[8];
    #pragma unroll
    for (int k = 0; k < 4; k++) {
        z[2 * k]     = a[k].x * iv + bf2f(rr[k] & 0xffffu);
        z[2 * k + 1] = a[k].y * iv + bf2f(rr[k] >> 16);
    }
    float mx = z[0];
    #pragma unroll
    for (int k = 1; k < 8; k++) mx = fmaxf(mx, z[k]);
    #pragma unroll
    for (int o = 1; o <= 4; o <<= 1) mx = fmaxf(mx, __shfl_xor(mx, o));
    float s = 0.0f;
    #pragma unroll
    for (int k = 0; k < 8; k++) s += __expf(z[k] - mx);
    #pragma unroll
    for (int o = 1; o <= 4; o <<= 1) s += __shfl_xor(s, o);
    float lse = mx + __logf(s);
    float* op = out + ((size_t)m * Nn + n) * 64 + sub * 8;
    *(float4*)op       = make_float4(z[0] - lse, z[1] - lse, z[2] - lse, z[3] - lse);
    *(float4*)(op + 4) = make_float4(z[4] - lse, z[5] - lse, z[6] - lse, z[7] - lse);
}

extern "C" void kernel_launch(void* const* d_in, const int* in_sizes, int n_in,
                              void* d_out, int out_size, void* d_ws, size_t ws_size,
                              hipStream_t stream) {
    const float* meta_x = (const float*)d_in[0];
    const int*   ei     = (const int*)d_in[1];
    const float* W1l    = (const float*)d_in[2];
    const float* W1r    = (const float*)d_in[3];
    const float* b1     = (const float*)d_in[4];
    const float* W2l    = (const float*)d_in[5];
    const float* W2r    = (const float*)d_in[6];
    const float* b2     = (const float*)d_in[7];
    float* out = (float*)d_out;

    const size_t nN = (size_t)METAc * Nn;

    float* inv  = (float*)d_ws;
    int*   cnt  = (int*)(inv + nN);
    int*   off  = cnt + nN;
    int*   cur  = off + nN;
    int*   csum = cur + nN;
    uint*  packed = (uint*)(csum + 64 * METAc);         // META*E packed (src|dst<<16)
    ushort* esrc = (ushort*)(packed + (size_t)METAc * Ee);
    uchar* t1   = (uchar*)(esrc + (size_t)METAc * Ee);  // fp8 e4m3, [nN][128]
    ushort* r1  = (ushort*)(t1 + nN * 128);
    ushort* h   = r1 + nN * 128;
    ushort* t2  = h + nN * 128;                         // bf16, [nN][64]
    ushort* r2  = t2 + nN * 64;
    ushort* Wcat1 = r2 + nN * 64;                       // META*256*128
    ushort* Wcat2 = Wcat1 + (size_t)METAc * 256 * 128;  // META*128*128

    (void)hipMemsetAsync(cnt, 0, nN * sizeof(int), stream);
    k_count<<<(METAc * (Ee / 4) + 255) / 256, 256, 0, stream>>>(ei, cnt, packed);
    k_chunksum<<<METAc * NCH, 1024, 0, stream>>>(cnt, csum);
    k_chunkscan<<<1, 256, 0, stream>>>(csum);
    k_scan<<<METAc * NCH, 1024, 0, stream>>>(cnt, csum, off, cur, inv);
    k_fill2<<<NXCD * FILL_WPX, 256, 0, stream>>>(packed, cur, esrc);
    k_wcat<<<(METAc * 384 * 128 + 255) / 256, 256, 0, stream>>>(W1l, W1r, W2l, W2r, Wcat1, Wcat2);

    k_mfma1<<<dim3((Nn + 127) / 128, METAc), 256, 0, stream>>>(meta_x, Wcat1, b1, t1, r1);
    k_agg_elu<<<(METAc * Nn / 8 + 255) / 256 * 64, 256, 0, stream>>>(t1, r1, off, cnt, inv, esrc, h);
    k_mfma2<<<dim3((Nn + 127) / 128, METAc), 256, 0, stream>>>(h, Wcat2, b2, t2, r2);
    k_agg_lsm<<<(METAc * Nn / 8 + 255) / 256 * 64, 256, 0, stream>>>(t2, r2, off, cnt, inv, esrc, out);
}